// Round 1
// baseline (226.362 us; speedup 1.0000x reference)
//
#include <hip/hip_runtime.h>
#include <math.h>

// ZINB decoder over edges.
// Strategy R1: 8 lanes per edge. Lane r loads k = c*32 + r*4 + [0,4) for c=0..3
// (coalesced 128B segments per instruction per row). W slices live in registers,
// amortized over a grid-stride loop. Butterfly reduce over 8 lanes, lane 0 does
// activations + 3 stores.

__global__ __launch_bounds__(256) void zinb_edge_kernel(
    const float* __restrict__ ufeats,     // [n_cells, 128]
    const float* __restrict__ ifeats,     // [n_genes, 128]
    const float* __restrict__ ge_factor,  // [n_genes]
    const float* __restrict__ sz_factor,  // [n_cells]
    const float* __restrict__ W_mean, const float* __restrict__ b_mean,
    const float* __restrict__ W_disp, const float* __restrict__ b_disp,
    const float* __restrict__ W_pi,   const float* __restrict__ b_pi,
    const int* __restrict__ src_idx,  // [E]
    const int* __restrict__ dst_idx,  // [E]
    float* __restrict__ out,          // [3E]: mu | disp | pi
    int E)
{
    const int r = threadIdx.x & 7;            // lane-in-group (0..7)
    const int slot = (blockIdx.x * blockDim.x + threadIdx.x) >> 3;
    const int n_slots = (gridDim.x * blockDim.x) >> 3;

    // Register-resident W slices: k = c*32 + r*4 .. +3
    float4 wm[4], wd[4], wp[4];
    {
        const float4* wm4 = (const float4*)W_mean + r;
        const float4* wd4 = (const float4*)W_disp + r;
        const float4* wp4 = (const float4*)W_pi   + r;
#pragma unroll
        for (int c = 0; c < 4; ++c) {
            wm[c] = wm4[c * 8];
            wd[c] = wd4[c * 8];
            wp[c] = wp4[c * 8];
        }
    }
    const float bm = b_mean[0], bd = b_disp[0], bp = b_pi[0];

    for (int e = slot; e < E; e += n_slots) {
        const int s = src_idx[e];
        const int g = dst_idx[e];

        const float4* u4 = (const float4*)(ufeats + (size_t)s * 128) + r;
        const float4* v4 = (const float4*)(ifeats + (size_t)g * 128) + r;

        float am = 0.f, ad = 0.f, ap = 0.f;
#pragma unroll
        for (int c = 0; c < 4; ++c) {
            float4 u = u4[c * 8];
            float4 v = v4[c * 8];
            float px = u.x * v.x;
            float py = u.y * v.y;
            float pz = u.z * v.z;
            float pw = u.w * v.w;
            am = fmaf(px, wm[c].x, am); am = fmaf(py, wm[c].y, am);
            am = fmaf(pz, wm[c].z, am); am = fmaf(pw, wm[c].w, am);
            ad = fmaf(px, wd[c].x, ad); ad = fmaf(py, wd[c].y, ad);
            ad = fmaf(pz, wd[c].z, ad); ad = fmaf(pw, wd[c].w, ad);
            ap = fmaf(px, wp[c].x, ap); ap = fmaf(py, wp[c].y, ap);
            ap = fmaf(pz, wp[c].z, ap); ap = fmaf(pw, wp[c].w, ap);
        }

        // Butterfly reduce across the 8 lanes of this group.
#pragma unroll
        for (int off = 1; off < 8; off <<= 1) {
            am += __shfl_xor(am, off);
            ad += __shfl_xor(ad, off);
            ap += __shfl_xor(ap, off);
        }

        if (r == 0) {
            const float gef = ge_factor[g];
            const float szf = sz_factor[s];

            // mu_ = sigmoid(am + bm)
            const float mu_ = 1.f / (1.f + __expf(-(am + bm)));
            // pi = sigmoid(ap + bp)
            const float pi = 1.f / (1.f + __expf(-(ap + bp)));
            // disp = clip(softplus(gef * (ad + bd)), 1e-4, 1e4)
            const float xd = gef * (ad + bd);
            const float sp = fmaxf(xd, 0.f) + __logf(1.f + __expf(-fabsf(xd)));
            const float disp = fminf(fmaxf(sp, 1e-4f), 1e4f);
            // mu = szf * clip(exp(gef * mu_) - 1, 1e-5, 1e6)
            const float mu = szf * fminf(fmaxf(__expf(gef * mu_) - 1.f, 1e-5f), 1e6f);

            out[e]                 = mu;
            out[(size_t)E + e]     = disp;
            out[(size_t)2 * E + e] = pi;
        }
    }
}

extern "C" void kernel_launch(void* const* d_in, const int* in_sizes, int n_in,
                              void* d_out, int out_size, void* d_ws, size_t ws_size,
                              hipStream_t stream) {
    const float* ufeats    = (const float*)d_in[0];
    const float* ifeats    = (const float*)d_in[1];
    const float* ge_factor = (const float*)d_in[2];
    const float* sz_factor = (const float*)d_in[3];
    const float* W_mean    = (const float*)d_in[4];
    const float* b_mean    = (const float*)d_in[5];
    const float* W_disp    = (const float*)d_in[6];
    const float* b_disp    = (const float*)d_in[7];
    const float* W_pi      = (const float*)d_in[8];
    const float* b_pi      = (const float*)d_in[9];
    const int*   src_idx   = (const int*)d_in[10];
    const int*   dst_idx   = (const int*)d_in[11];
    float* out = (float*)d_out;

    const int E = in_sizes[10];

    const int threads = 256;
    const int blocks  = 2048;  // grid-stride; 8 blocks/CU target, ~30 edges/slot
    hipLaunchKernelGGL(zinb_edge_kernel, dim3(blocks), dim3(threads), 0, stream,
                       ufeats, ifeats, ge_factor, sz_factor,
                       W_mean, b_mean, W_disp, b_disp, W_pi, b_pi,
                       src_idx, dst_idx, out, E);
}

// Round 2
// 155.887 us; speedup vs baseline: 1.4521x; 1.4521x over previous
//
#include <hip/hip_runtime.h>
#include <math.h>

// R2: f16 feature tables in d_ws (3 MB total -> L2-resident per XCD), halving
// gather bytes vs f32. 8 lanes per edge, 2 edges per group-iteration for MLP.
// W vectors stay f32 in registers. Fallback to pure-f32 path if ws too small.

typedef _Float16 h2 __attribute__((ext_vector_type(2)));
union U16 { uint4 u; h2 h[4]; };
union HU { uint u; h2 h; };

// ---------------- conversion kernel: f32 -> f16 (4 elems/thread) -------------
__global__ __launch_bounds__(256) void cvt_f16_kernel(
    const float4* __restrict__ src, uint2* __restrict__ dst, int n4)
{
    int i = blockIdx.x * blockDim.x + threadIdx.x;
    if (i >= n4) return;
    float4 f = src[i];
    HU a, b;
    a.h = h2{(_Float16)f.x, (_Float16)f.y};
    b.h = h2{(_Float16)f.z, (_Float16)f.w};
    dst[i] = make_uint2(a.u, b.u);
}

// ---------------- main edge kernel (f16 features) ----------------------------
__global__ __launch_bounds__(256) void zinb_edge_f16_kernel(
    const _Float16* __restrict__ uhalf,   // [n_cells, 128]
    const _Float16* __restrict__ ihalf,   // [n_genes, 128]
    const float* __restrict__ ge_factor,  // [n_genes]
    const float* __restrict__ sz_factor,  // [n_cells]
    const float* __restrict__ W_mean, const float* __restrict__ b_mean,
    const float* __restrict__ W_disp, const float* __restrict__ b_disp,
    const float* __restrict__ W_pi,   const float* __restrict__ b_pi,
    const int* __restrict__ src_idx,
    const int* __restrict__ dst_idx,
    float* __restrict__ out,              // [3E]: mu | disp | pi
    int E)
{
    const int r = threadIdx.x & 7;
    const int slot = (blockIdx.x * blockDim.x + threadIdx.x) >> 3;
    const int n_slots = (gridDim.x * blockDim.x) >> 3;

    // W slices: lane r owns elems c*64 + r*8 + t, c in {0,1}, t in [0,8)
    float wm[16], wd[16], wp[16];
#pragma unroll
    for (int c = 0; c < 2; ++c)
#pragma unroll
        for (int t = 0; t < 8; ++t) {
            int k = c * 64 + r * 8 + t;
            wm[c * 8 + t] = W_mean[k];
            wd[c * 8 + t] = W_disp[k];
            wp[c * 8 + t] = W_pi[k];
        }
    const float bm = b_mean[0], bd = b_disp[0], bp = b_pi[0];

    const int npairs = E >> 1;   // E is even (2,000,000); guard below anyway
    for (int p = slot; p < npairs; p += n_slots) {
        const int e0 = 2 * p;
        const int e1 = (e0 + 1 < E) ? e0 + 1 : e0;
        const int s0 = src_idx[e0], s1 = src_idx[e1];
        const int g0 = dst_idx[e0], g1 = dst_idx[e1];

        const uint4* u0p = (const uint4*)(uhalf + (size_t)s0 * 128);
        const uint4* v0p = (const uint4*)(ihalf + (size_t)g0 * 128);
        const uint4* u1p = (const uint4*)(uhalf + (size_t)s1 * 128);
        const uint4* v1p = (const uint4*)(ihalf + (size_t)g1 * 128);

        // 8 independent 16B loads in flight
        U16 ua, ub, va, vb, uc, ud, vc, vd2;
        ua.u = u0p[r];     va.u = v0p[r];
        ub.u = u0p[r + 8]; vb.u = v0p[r + 8];
        uc.u = u1p[r];     vc.u = v1p[r];
        ud.u = u1p[r + 8]; vd2.u = v1p[r + 8];

        float am0 = 0.f, ad0 = 0.f, ap0 = 0.f;
        float am1 = 0.f, ad1 = 0.f, ap1 = 0.f;
#pragma unroll
        for (int j = 0; j < 4; ++j) {
            // edge0 chunk0
            h2 pa = ua.h[j] * va.h[j];
            float pax = (float)pa.x, pay = (float)pa.y;
            int k0 = 2 * j;
            am0 = fmaf(pax, wm[k0], fmaf(pay, wm[k0 + 1], am0));
            ad0 = fmaf(pax, wd[k0], fmaf(pay, wd[k0 + 1], ad0));
            ap0 = fmaf(pax, wp[k0], fmaf(pay, wp[k0 + 1], ap0));
            // edge0 chunk1
            h2 pb = ub.h[j] * vb.h[j];
            float pbx = (float)pb.x, pby = (float)pb.y;
            int k1 = 8 + 2 * j;
            am0 = fmaf(pbx, wm[k1], fmaf(pby, wm[k1 + 1], am0));
            ad0 = fmaf(pbx, wd[k1], fmaf(pby, wd[k1 + 1], ad0));
            ap0 = fmaf(pbx, wp[k1], fmaf(pby, wp[k1 + 1], ap0));
            // edge1 chunk0
            h2 pc = uc.h[j] * vc.h[j];
            float pcx = (float)pc.x, pcy = (float)pc.y;
            am1 = fmaf(pcx, wm[k0], fmaf(pcy, wm[k0 + 1], am1));
            ad1 = fmaf(pcx, wd[k0], fmaf(pcy, wd[k0 + 1], ad1));
            ap1 = fmaf(pcx, wp[k0], fmaf(pcy, wp[k0 + 1], ap1));
            // edge1 chunk1
            h2 pd = ud.h[j] * vd2.h[j];
            float pdx = (float)pd.x, pdy = (float)pd.y;
            am1 = fmaf(pdx, wm[k1], fmaf(pdy, wm[k1 + 1], am1));
            ad1 = fmaf(pdx, wd[k1], fmaf(pdy, wd[k1 + 1], ad1));
            ap1 = fmaf(pdx, wp[k1], fmaf(pdy, wp[k1 + 1], ap1));
        }

#pragma unroll
        for (int off = 1; off < 8; off <<= 1) {
            am0 += __shfl_xor(am0, off); ad0 += __shfl_xor(ad0, off); ap0 += __shfl_xor(ap0, off);
            am1 += __shfl_xor(am1, off); ad1 += __shfl_xor(ad1, off); ap1 += __shfl_xor(ap1, off);
        }

        if ((r & 3) == 0) {
            const int  e = (r == 0) ? e0 : e1;
            const int  s = (r == 0) ? s0 : s1;
            const int  g = (r == 0) ? g0 : g1;
            const float am = (r == 0) ? am0 : am1;
            const float ad = (r == 0) ? ad0 : ad1;
            const float ap = (r == 0) ? ap0 : ap1;

            const float gef = ge_factor[g];
            const float szf = sz_factor[s];

            const float mu_ = 1.f / (1.f + __expf(-(am + bm)));
            const float pi  = 1.f / (1.f + __expf(-(ap + bp)));
            const float xd  = gef * (ad + bd);
            const float sp  = fmaxf(xd, 0.f) + __logf(1.f + __expf(-fabsf(xd)));
            const float disp = fminf(fmaxf(sp, 1e-4f), 1e4f);
            const float mu = szf * fminf(fmaxf(__expf(gef * mu_) - 1.f, 1e-5f), 1e6f);

            out[e]                 = mu;
            out[(size_t)E + e]     = disp;
            out[(size_t)2 * E + e] = pi;
        }
    }
}

// ---------------- fallback: R1 pure-f32 kernel -------------------------------
__global__ __launch_bounds__(256) void zinb_edge_f32_kernel(
    const float* __restrict__ ufeats, const float* __restrict__ ifeats,
    const float* __restrict__ ge_factor, const float* __restrict__ sz_factor,
    const float* __restrict__ W_mean, const float* __restrict__ b_mean,
    const float* __restrict__ W_disp, const float* __restrict__ b_disp,
    const float* __restrict__ W_pi,   const float* __restrict__ b_pi,
    const int* __restrict__ src_idx, const int* __restrict__ dst_idx,
    float* __restrict__ out, int E)
{
    const int r = threadIdx.x & 7;
    const int slot = (blockIdx.x * blockDim.x + threadIdx.x) >> 3;
    const int n_slots = (gridDim.x * blockDim.x) >> 3;

    float4 wm[4], wd[4], wp[4];
    {
        const float4* wm4 = (const float4*)W_mean + r;
        const float4* wd4 = (const float4*)W_disp + r;
        const float4* wp4 = (const float4*)W_pi   + r;
#pragma unroll
        for (int c = 0; c < 4; ++c) { wm[c] = wm4[c*8]; wd[c] = wd4[c*8]; wp[c] = wp4[c*8]; }
    }
    const float bm = b_mean[0], bd = b_disp[0], bp = b_pi[0];

    for (int e = slot; e < E; e += n_slots) {
        const int s = src_idx[e];
        const int g = dst_idx[e];
        const float4* u4 = (const float4*)(ufeats + (size_t)s * 128) + r;
        const float4* v4 = (const float4*)(ifeats + (size_t)g * 128) + r;
        float am = 0.f, ad = 0.f, ap = 0.f;
#pragma unroll
        for (int c = 0; c < 4; ++c) {
            float4 u = u4[c*8]; float4 v = v4[c*8];
            float px = u.x*v.x, py = u.y*v.y, pz = u.z*v.z, pw = u.w*v.w;
            am = fmaf(px, wm[c].x, am); am = fmaf(py, wm[c].y, am);
            am = fmaf(pz, wm[c].z, am); am = fmaf(pw, wm[c].w, am);
            ad = fmaf(px, wd[c].x, ad); ad = fmaf(py, wd[c].y, ad);
            ad = fmaf(pz, wd[c].z, ad); ad = fmaf(pw, wd[c].w, ad);
            ap = fmaf(px, wp[c].x, ap); ap = fmaf(py, wp[c].y, ap);
            ap = fmaf(pz, wp[c].z, ap); ap = fmaf(pw, wp[c].w, ap);
        }
#pragma unroll
        for (int off = 1; off < 8; off <<= 1) {
            am += __shfl_xor(am, off); ad += __shfl_xor(ad, off); ap += __shfl_xor(ap, off);
        }
        if (r == 0) {
            const float gef = ge_factor[g];
            const float szf = sz_factor[s];
            const float mu_ = 1.f / (1.f + __expf(-(am + bm)));
            const float pi  = 1.f / (1.f + __expf(-(ap + bp)));
            const float xd  = gef * (ad + bd);
            const float sp  = fmaxf(xd, 0.f) + __logf(1.f + __expf(-fabsf(xd)));
            const float disp = fminf(fmaxf(sp, 1e-4f), 1e4f);
            const float mu = szf * fminf(fmaxf(__expf(gef * mu_) - 1.f, 1e-5f), 1e6f);
            out[e] = mu; out[(size_t)E + e] = disp; out[(size_t)2*E + e] = pi;
        }
    }
}

extern "C" void kernel_launch(void* const* d_in, const int* in_sizes, int n_in,
                              void* d_out, int out_size, void* d_ws, size_t ws_size,
                              hipStream_t stream) {
    const float* ufeats    = (const float*)d_in[0];
    const float* ifeats    = (const float*)d_in[1];
    const float* ge_factor = (const float*)d_in[2];
    const float* sz_factor = (const float*)d_in[3];
    const float* W_mean    = (const float*)d_in[4];
    const float* b_mean    = (const float*)d_in[5];
    const float* W_disp    = (const float*)d_in[6];
    const float* b_disp    = (const float*)d_in[7];
    const float* W_pi      = (const float*)d_in[8];
    const float* b_pi      = (const float*)d_in[9];
    const int*   src_idx   = (const int*)d_in[10];
    const int*   dst_idx   = (const int*)d_in[11];
    float* out = (float*)d_out;

    const int E       = in_sizes[10];
    const int n_cells = in_sizes[0] / 128;
    const int n_genes = in_sizes[1] / 128;

    const size_t u_elems = (size_t)n_cells * 128;
    const size_t i_elems = (size_t)n_genes * 128;
    const size_t ws_needed = (u_elems + i_elems) * sizeof(_Float16);

    if (ws_size >= ws_needed) {
        _Float16* uhalf = (_Float16*)d_ws;
        _Float16* ihalf = uhalf + u_elems;

        const int un4 = (int)(u_elems / 4);
        const int in4 = (int)(i_elems / 4);
        hipLaunchKernelGGL(cvt_f16_kernel, dim3((un4 + 255) / 256), dim3(256), 0, stream,
                           (const float4*)ufeats, (uint2*)uhalf, un4);
        hipLaunchKernelGGL(cvt_f16_kernel, dim3((in4 + 255) / 256), dim3(256), 0, stream,
                           (const float4*)ifeats, (uint2*)ihalf, in4);

        hipLaunchKernelGGL(zinb_edge_f16_kernel, dim3(2048), dim3(256), 0, stream,
                           uhalf, ihalf, ge_factor, sz_factor,
                           W_mean, b_mean, W_disp, b_disp, W_pi, b_pi,
                           src_idx, dst_idx, out, E);
    } else {
        hipLaunchKernelGGL(zinb_edge_f32_kernel, dim3(2048), dim3(256), 0, stream,
                           ufeats, ifeats, ge_factor, sz_factor,
                           W_mean, b_mean, W_disp, b_disp, W_pi, b_pi,
                           src_idx, dst_idx, out, E);
    }
}